// Round 5
// baseline (210.357 us; speedup 1.0000x reference)
//
#include <hip/hip_runtime.h>
#include <hip/hip_bf16.h>
#include <stdint.h>

// W-MSA on flat-reinterpreted windows.
// pp = n1<<10|n3<<6|w2<<3|w4  ->  P = n1<<10|w2<<7|n3<<3|w4
// QKV/proj are plain GEMMs on x.view(B*16384,384) in pp-row order; each
// attention (h,n') block is a contiguous [64][32] chunk of [pp][c] arrays.
// qkv_fused: per block, the 128-row A-tile (permuted+cast from fp32 x) is
// staged ONCE into LDS (96KB, granule-swizzled) and reused for all 9 N-tiles;
// only B streams per K-step (glds, dbuf, counted vmcnt).

typedef __bf16 bf16_t;
typedef __bf16 bf16x8 __attribute__((ext_vector_type(8)));
typedef float f32x4 __attribute__((ext_vector_type(4)));

__device__ __forceinline__ void gload_lds16(const void* g, void* l) {
  __builtin_amdgcn_global_load_lds((__attribute__((address_space(1))) void*)(g),
                                   (__attribute__((address_space(3))) void*)(l),
                                   16, 0, 0);
}

// ---------------- weight fp32->bf16 (Wq|Wk|Wv concatenated, then Wp) -------
__global__ __launch_bounds__(256) void convw_kernel(
    const float* __restrict__ wq, const float* __restrict__ wk,
    const float* __restrict__ wv, const float* __restrict__ wp,
    bf16_t* __restrict__ oq, bf16_t* __restrict__ ok,
    bf16_t* __restrict__ ov, bf16_t* __restrict__ op_) {
  int i = blockIdx.x * 256 + threadIdx.x;  // grid covers exactly 147456
  oq[i] = (bf16_t)wq[i];
  ok[i] = (bf16_t)wk[i];
  ov[i] = (bf16_t)wv[i];
  op_[i] = (bf16_t)wp[i];
}

// ---------------- fused prep + QKV GEMM ----------------
// Block: 128 pixel-rows (one m-tile), loops 9 j-tiles x 12 K-steps.
// LDS: A [128][48 granules of 8 bf16] = 96KB (persistent, swizzled)
//      B dbuf 2 x [128][4 slots of 8 bf16] = 16KB
__global__ __launch_bounds__(256) void qkv_fused(
    const float* __restrict__ x, const bf16_t* __restrict__ Wcat,
    const float* __restrict__ bq, const float* __restrict__ bk,
    const float* __restrict__ bv,
    bf16_t* __restrict__ Qs, bf16_t* __restrict__ Ks, bf16_t* __restrict__ Vs) {
  extern __shared__ __align__(16) char smem[];
  bf16_t* As = (bf16_t*)smem;            // 98304 B
  bf16_t* Bs = (bf16_t*)(smem + 98304);  // 2 x 8192 B

  const int tid = threadIdx.x;
  const int lane = tid & 63, wvv = tid >> 6;
  const int l15 = lane & 15, hi = lane >> 4;
  const int wr = wvv >> 1, wc = wvv & 1;
  const int slotB = hi ^ ((l15 >> 1) & 3);           // B read slot (as R2)
  const int sswB = (lane & 3) ^ ((lane >> 3) & 3);   // B source slot (as R2)

  const int m0 = blockIdx.x * 128;
  const int b = m0 >> 14;
  const int pp0 = m0 & 16383;

  auto stageB = [&](int s) {
    int jj = s / 12, kk = s - jj * 12;
    const bf16_t* src = Wcat + (size_t)jj * 49152 + kk * 32;
    bf16_t* dst = Bs + (s & 1) * 4096;
#pragma unroll
    for (int h = 0; h < 2; ++h) {
      int qq = wvv * 128 + h * 64 + lane;
      int row = qq >> 2;
      gload_lds16(src + (size_t)row * 384 + sswB * 8,
                  (char*)dst + (wvv * 128 + h * 64) * 16);
    }
  };

  stageB(0);
  stageB(1);

  // ---- A stage: once per block. granule (r,g) stored at slot g^(r&7). ----
  {
    float4 ca[6][2], cb2[6][2];
    auto issue = [&](float4 (&buf)[6][2], int c) {
#pragma unroll
      for (int u = 0; u < 6; ++u) {
        unsigned gid = (unsigned)(c * 6 + u) * 256u + (unsigned)tid;
        unsigned r = gid / 48u, g = gid - r * 48u;
        int pp = pp0 + (int)r;
        int n1 = pp >> 10, n3 = (pp >> 6) & 15, w2 = (pp >> 3) & 7, w4 = pp & 7;
        const float* src = x +
            (size_t)((b << 14) | (n1 << 10) | (w2 << 7) | (n3 << 3) | w4) * 384 +
            g * 8;
        buf[u][0] = *(const float4*)(src);
        buf[u][1] = *(const float4*)(src + 4);
      }
    };
    auto consume = [&](float4 (&buf)[6][2], int c) {
#pragma unroll
      for (int u = 0; u < 6; ++u) {
        unsigned gid = (unsigned)(c * 6 + u) * 256u + (unsigned)tid;
        unsigned r = gid / 48u, g = gid - r * 48u;
        bf16x8 p;
        p[0] = (bf16_t)buf[u][0].x; p[1] = (bf16_t)buf[u][0].y;
        p[2] = (bf16_t)buf[u][0].z; p[3] = (bf16_t)buf[u][0].w;
        p[4] = (bf16_t)buf[u][1].x; p[5] = (bf16_t)buf[u][1].y;
        p[6] = (bf16_t)buf[u][1].z; p[7] = (bf16_t)buf[u][1].w;
        *(bf16x8*)(As + r * 384 + (g ^ (r & 7u)) * 8) = p;
      }
    };
    issue(ca, 0);
    issue(cb2, 1);
    consume(ca, 0);
    issue(ca, 2);
    consume(cb2, 1);
    issue(cb2, 3);
    consume(ca, 2);
    consume(cb2, 3);
  }
  __syncthreads();  // A visible to all waves; prologue B stages also drained

  const f32x4 fz = {0.f, 0.f, 0.f, 0.f};
  f32x4 acc[4][4] = {};

  for (int s = 0; s < 108; ++s) {
    const int j = s / 12;
    const int kt = s - j * 12;
    // stage(s) must be landed; keep stage(s+1) [2 glds] in flight
    if (s == 107) asm volatile("s_waitcnt vmcnt(0)" ::: "memory");
    else          asm volatile("s_waitcnt vmcnt(2)" ::: "memory");
    __builtin_amdgcn_s_barrier();

    const bf16_t* Bb = Bs + (s & 1) * 4096;
    bf16x8 a[4], bfr[4];
#pragma unroll
    for (int i = 0; i < 4; ++i) {
      int r = wr * 64 + i * 16 + l15;
      int gr = (4 * kt + hi) ^ (l15 & 7);
      a[i] = *(const bf16x8*)(As + r * 384 + gr * 8);
      bfr[i] = *(const bf16x8*)(Bb + (wc * 64 + i * 16 + l15) * 32 + slotB * 8);
    }
#pragma unroll
    for (int mi = 0; mi < 4; ++mi)
#pragma unroll
      for (int ni = 0; ni < 4; ++ni)
        acc[mi][ni] = __builtin_amdgcn_mfma_f32_16x16x32_bf16(a[mi], bfr[ni],
                                                              acc[mi][ni], 0, 0, 0);
    asm volatile("s_waitcnt lgkmcnt(0)" ::: "memory");
    __builtin_amdgcn_sched_barrier(0);
    __builtin_amdgcn_s_barrier();
    if (s + 2 < 108) stageB(s + 2);

    if (kt == 11) {  // epilogue for j-tile; then reset acc
      const float* bias = (j < 3) ? bq : (j < 6) ? bk : bv;
      bf16_t* Out = (j < 3) ? Qs : (j < 6) ? Ks : Vs;
      const int cb = (j % 3) * 128;
#pragma unroll
      for (int ni = 0; ni < 4; ++ni) {
        int ch = wc * 64 + ni * 16 + l15;
        float bv_ = bias[cb + ch];
#pragma unroll
        for (int mi = 0; mi < 4; ++mi)
#pragma unroll
          for (int rr = 0; rr < 4; ++rr) {
            int row = m0 + wr * 64 + mi * 16 + hi * 4 + rr;
            Out[(size_t)row * 384 + cb + ch] = (bf16_t)(acc[mi][ni][rr] + bv_);
          }
      }
#pragma unroll
      for (int mi = 0; mi < 4; ++mi)
#pragma unroll
        for (int ni = 0; ni < 4; ++ni) acc[mi][ni] = fz;
    }
  }
}

// ---------------- generic bf16 GEMM mainloop (proj) ----------------
__device__ __forceinline__ void stage_tile(const bf16_t* __restrict__ A,
                                           const bf16_t* __restrict__ B,
                                           bf16_t* As, bf16_t* Bs, int k0, int tid) {
  const int lane = tid & 63, wvv = tid >> 6;
  const int s = (lane & 3) ^ ((lane >> 3) & 3);
#pragma unroll
  for (int j = 0; j < 2; ++j) {
    int q = wvv * 128 + j * 64 + lane;
    int row = q >> 2;
    gload_lds16(A + (size_t)row * 384 + k0 + s * 8,
                (char*)As + (wvv * 128 + j * 64) * 16);
    gload_lds16(B + (size_t)row * 384 + k0 + s * 8,
                (char*)Bs + (wvv * 128 + j * 64) * 16);
  }
}

__device__ __forceinline__ void gemm_mainloop(const bf16_t* __restrict__ Arows,
                                              const bf16_t* __restrict__ Brows,
                                              bf16_t* As, bf16_t* Bs,
                                              int tid, f32x4 acc[4][4]) {
  const int lane = tid & 63;
  const int l15 = lane & 15, hi = lane >> 4;
  const int wr = (tid >> 6) >> 1, wc = (tid >> 6) & 1;
  const int slot = hi ^ ((l15 >> 1) & 3);
  stage_tile(Arows, Brows, As, Bs, 0, tid);
  stage_tile(Arows, Brows, As + 4096, Bs + 4096, 32, tid);
#pragma unroll
  for (int kt = 0; kt < 12; ++kt) {
    bf16_t* Ab = As + (kt & 1) * 4096;
    bf16_t* Bb = Bs + (kt & 1) * 4096;
    if (kt == 11) asm volatile("s_waitcnt vmcnt(0)" ::: "memory");
    else          asm volatile("s_waitcnt vmcnt(4)" ::: "memory");
    __builtin_amdgcn_s_barrier();
    bf16x8 a[4], bfr[4];
#pragma unroll
    for (int i = 0; i < 4; ++i) {
      a[i] = *(const bf16x8*)(Ab + (wr * 64 + i * 16 + l15) * 32 + slot * 8);
      bfr[i] = *(const bf16x8*)(Bb + (wc * 64 + i * 16 + l15) * 32 + slot * 8);
    }
#pragma unroll
    for (int mi = 0; mi < 4; ++mi)
#pragma unroll
      for (int ni = 0; ni < 4; ++ni)
        acc[mi][ni] = __builtin_amdgcn_mfma_f32_16x16x32_bf16(a[mi], bfr[ni],
                                                              acc[mi][ni], 0, 0, 0);
    asm volatile("s_waitcnt lgkmcnt(0)" ::: "memory");
    __builtin_amdgcn_sched_barrier(0);
    __builtin_amdgcn_s_barrier();
    if (kt + 2 < 12)
      stage_tile(Arows, Brows, Ab, Bb, (kt + 2) * 32, tid);
  }
}

// ---------------- attention: one wave per (b,h,n') block ----------------
__global__ __launch_bounds__(64) void attn_kernel(const bf16_t* __restrict__ Q,
                                                  const bf16_t* __restrict__ K,
                                                  const bf16_t* __restrict__ V,
                                                  bf16_t* __restrict__ O) {
  const size_t base = (size_t)blockIdx.x * 2048;
  const bf16_t* q = Q + base;
  const bf16_t* k = K + base;
  const bf16_t* v = V + base;
  bf16_t* o = O + base;
  const int lane = threadIdx.x;
  const int l15 = lane & 15, hi = lane >> 4;

  __shared__ __align__(16) bf16_t Vt[32][72];  // V transposed [d][k]
  __shared__ __align__(16) bf16_t Ps[64][72];  // P (attn weights) [q][k]

#pragma unroll
  for (int j = 0; j < 4; ++j) {
    bf16x8 vv = *(const bf16x8*)(v + lane * 32 + j * 8);
#pragma unroll
    for (int e = 0; e < 8; ++e) Vt[j * 8 + e][lane] = vv[e];
  }

  bf16x8 aQ[4], bK[4];
#pragma unroll
  for (int i = 0; i < 4; ++i) {
    aQ[i] = *(const bf16x8*)(q + (i * 16 + l15) * 32 + hi * 8);
    bK[i] = *(const bf16x8*)(k + (i * 16 + l15) * 32 + hi * 8);
  }
  f32x4 sc[4][4] = {};
#pragma unroll
  for (int mi = 0; mi < 4; ++mi)
#pragma unroll
    for (int ni = 0; ni < 4; ++ni)
      sc[mi][ni] = __builtin_amdgcn_mfma_f32_16x16x32_bf16(aQ[mi], bK[ni],
                                                           sc[mi][ni], 0, 0, 0);

  const float SCALE = 0.17677669529663687f;  // 32^-0.5
  float rs[4][4];
#pragma unroll
  for (int mi = 0; mi < 4; ++mi) {
#pragma unroll
    for (int r = 0; r < 4; ++r) {
      float s0 = sc[mi][0][r] * SCALE, s1 = sc[mi][1][r] * SCALE;
      float s2 = sc[mi][2][r] * SCALE, s3 = sc[mi][3][r] * SCALE;
      float mx = fmaxf(fmaxf(s0, s1), fmaxf(s2, s3));
      mx = fmaxf(mx, __shfl_xor(mx, 1));
      mx = fmaxf(mx, __shfl_xor(mx, 2));
      mx = fmaxf(mx, __shfl_xor(mx, 4));
      mx = fmaxf(mx, __shfl_xor(mx, 8));
      float p0 = __expf(s0 - mx), p1 = __expf(s1 - mx);
      float p2 = __expf(s2 - mx), p3 = __expf(s3 - mx);
      int row = mi * 16 + hi * 4 + r;
      Ps[row][0 + l15] = (bf16_t)p0;
      Ps[row][16 + l15] = (bf16_t)p1;
      Ps[row][32 + l15] = (bf16_t)p2;
      Ps[row][48 + l15] = (bf16_t)p3;
      float sum = p0 + p1 + p2 + p3;
      sum += __shfl_xor(sum, 1);
      sum += __shfl_xor(sum, 2);
      sum += __shfl_xor(sum, 4);
      sum += __shfl_xor(sum, 8);
      rs[mi][r] = sum;
    }
  }
  __syncthreads();

  f32x4 oacc[4][2] = {};
#pragma unroll
  for (int mi = 0; mi < 4; ++mi)
#pragma unroll
    for (int ks = 0; ks < 2; ++ks) {
      bf16x8 aP = *(const bf16x8*)(&Ps[mi * 16 + l15][ks * 32 + hi * 8]);
#pragma unroll
      for (int n2 = 0; n2 < 2; ++n2) {
        bf16x8 bV = *(const bf16x8*)(&Vt[n2 * 16 + l15][ks * 32 + hi * 8]);
        oacc[mi][n2] = __builtin_amdgcn_mfma_f32_16x16x32_bf16(aP, bV,
                                                               oacc[mi][n2], 0, 0, 0);
      }
    }
#pragma unroll
  for (int mi = 0; mi < 4; ++mi)
#pragma unroll
    for (int n2 = 0; n2 < 2; ++n2)
#pragma unroll
      for (int r = 0; r < 4; ++r) {
        int row = mi * 16 + hi * 4 + r;
        o[row * 32 + n2 * 16 + l15] = (bf16_t)(oacc[mi][n2][r] / rs[mi][r]);
      }
}

// ---------------- output projection GEMM ----------------
// Grid remap: 3 consecutive slots per XCD share the same O (B-operand) tile.
__global__ __launch_bounds__(256) void proj_gemm(const bf16_t* __restrict__ Wpb,
                                                 const bf16_t* __restrict__ O,
                                                 const float* __restrict__ bp,
                                                 float* __restrict__ y) {
  __shared__ __align__(16) bf16_t As[2 * 128 * 32];
  __shared__ __align__(16) bf16_t Bs[2 * 128 * 32];
  const int tid = threadIdx.x;
  const int F = blockIdx.x;            // 1536 = 8 xcd * 3 j * 64 gq
  const int xcd = F & 7;
  const int t = F >> 3;
  const int j = t % 3;                 // out-chan tile
  const int gq = t / 3;
  const int g = gq * 8 + xcd;          // 0..511 -> (pix tile, batch)
  const int n0 = (g & 127) * 128;      // pixels within batch
  const int b = g >> 7;
  const int m0 = j * 128;              // out channels
  f32x4 acc[4][4] = {};
  gemm_mainloop(Wpb + (size_t)m0 * 384, O + ((size_t)b * 16384 + n0) * 384,
                As, Bs, tid, acc);
  const int lane = tid & 63, wvv = tid >> 6;
  const int l15 = lane & 15, hi = lane >> 4;
  const int wr = wvv >> 1, wc = wvv & 1;
  float* yb = y + (size_t)b * 6291456;
#pragma unroll
  for (int mi = 0; mi < 4; ++mi)
#pragma unroll
    for (int r = 0; r < 4; ++r) {
      int och = m0 + wr * 64 + mi * 16 + hi * 4 + r;
      float bpv = bp[och];
#pragma unroll
      for (int ni = 0; ni < 4; ++ni) {
        int pix = n0 + wc * 64 + ni * 16 + l15;
        yb[(size_t)och * 16384 + pix] = acc[mi][ni][r] + bpv;
      }
    }
}

extern "C" void kernel_launch(void* const* d_in, const int* in_sizes, int n_in,
                              void* d_out, int out_size, void* d_ws, size_t ws_size,
                              hipStream_t stream) {
  const float* x  = (const float*)d_in[0];
  const float* Wq = (const float*)d_in[1];
  const float* bq = (const float*)d_in[2];
  const float* Wk = (const float*)d_in[3];
  const float* bk = (const float*)d_in[4];
  const float* Wv = (const float*)d_in[5];
  const float* bv = (const float*)d_in[6];
  const float* Wp = (const float*)d_in[7];
  const float* bp = (const float*)d_in[8];
  float* y = (float*)d_out;

  char* ws = (char*)d_ws;
  const size_t SZ = 50331648;               // 65536*384*2 bytes
  bf16_t* Ob  = (bf16_t*)(ws);              // attn output [65536][384]
  bf16_t* Vs  = (bf16_t*)(ws + SZ);
  bf16_t* Wcat = (bf16_t*)(ws + 2 * SZ);    // [1152][384] = Wq|Wk|Wv rows
  bf16_t* Wkb = Wcat + 147456;
  bf16_t* Wvb = Wkb + 147456;
  bf16_t* Wpb = Wvb + 147456;
  bf16_t* Qs  = (bf16_t*)d_out;             // stash Q,K in d_out (exact fit)
  bf16_t* Ks  = (bf16_t*)((char*)d_out + SZ);

  hipFuncSetAttribute((const void*)qkv_fused,
                      hipFuncAttributeMaxDynamicSharedMemorySize, 114688);

  convw_kernel<<<576, 256, 0, stream>>>(Wq, Wk, Wv, Wp, Wcat, Wkb, Wvb, Wpb);
  qkv_fused<<<512, 256, 114688, stream>>>(x, Wcat, bq, bk, bv, Qs, Ks, Vs);
  attn_kernel<<<12288, 64, 0, stream>>>(Qs, Ks, Vs, Ob);
  proj_gemm<<<1536, 256, 0, stream>>>(Wpb, Ob, bp, y);
}